// Round 4
// baseline (180.709 us; speedup 1.0000x reference)
//
#include <hip/hip_runtime.h>

typedef unsigned short ushort_t;
typedef __attribute__((ext_vector_type(8))) short shortx8;
typedef __attribute__((ext_vector_type(4))) float floatx4;
typedef __attribute__((ext_vector_type(2))) float floatx2;

#define NS 0.1f

__device__ __forceinline__ ushort_t f2bf_rne(float f) {
  union { float f; unsigned int u; } v; v.f = f;
  unsigned int r = v.u + 0x7FFFu + ((v.u >> 16) & 1u);
  return (ushort_t)(r >> 16);
}
// pack two f32 -> bf16x2 (round-half-up) in one v_perm: low16=bf(a), high16=bf(b)
__device__ __forceinline__ unsigned int pk2bf(float a, float b) {
  union { float f; unsigned int u; } x, y; x.f = a; y.f = b;
  return __builtin_amdgcn_perm(y.u + 0x8000u, x.u + 0x8000u, 0x07060302u);
}
__device__ __forceinline__ ushort_t f2bf_rhu(float f) {
  union { float f; unsigned int u; } v; v.f = f;
  return (ushort_t)((v.u + 0x8000u) >> 16);
}
__device__ __forceinline__ float lk(float x) { return fmaxf(x, NS * x); }
__device__ __forceinline__ floatx2 lk2(floatx2 v) {
  return __builtin_elementwise_max(v, v * (floatx2){NS, NS});
}

// fragment-linear weight layout: element e = f*8+j, f = (s*NT + t)*64 + lane,
// value = W[k = s*32 + (lane>>4)*8 + j][n = t*16 + (lane&15)]  (W is KxN row-major)
__global__ __launch_bounds__(256) void prep_w(
    const float* __restrict__ W_e1, const float* __restrict__ W_e2,
    const float* __restrict__ W_h1, const float* __restrict__ W_h2,
    ushort_t* __restrict__ wijf, ushort_t* __restrict__ we2f,
    ushort_t* __restrict__ wh1f, ushort_t* __restrict__ wh2f) {
  int e = blockIdx.x * 256 + threadIdx.x;
  int which, le;
  if (e < 32768) { which = 0; le = e; }
  else if (e < 49152) { which = 1; le = e - 32768; }
  else if (e < 81920) { which = 2; le = e - 49152; }
  else { which = 3; le = e - 81920; }
  const int NT = (which == 0) ? 16 : 8;
  int f = le >> 3, j = le & 7;
  int lane = f & 63, ft = f >> 6;
  int t = ft % NT, s = ft / NT;
  int n = t * 16 + (lane & 15), k = s * 32 + (lane >> 4) * 8 + j;
  float v; ushort_t* d;
  if (which == 0) { v = (n < 128) ? W_e1[k * 128 + n] : W_e1[(128 + k) * 128 + (n - 128)]; d = wijf; }
  else if (which == 1) { v = W_e2[k * 128 + n]; d = we2f; }
  else if (which == 2) { v = W_h1[k * 128 + n]; d = wh1f; }
  else { v = W_h2[k * 128 + n]; d = wh2f; }
  d[le] = f2bf_rne(v);
}

// proj epilogue store: ti plain [m][n<128]; tj fragment-linear for the edge kernel:
// tjf[(((b*4 + s)*256 + j)*4 + lg)*8 + j8] = tj[j][k], k = s*32+lg*8+j8
__device__ __forceinline__ void proj_store(float v, int m, int n,
                                           float* __restrict__ ti, float* __restrict__ tjf) {
  if (n < 128) {
    ti[(size_t)m * 128 + n] = v;
  } else {
    int k = n - 128, b = m >> 8, j = m & 255;
    int s = k >> 5, lg2 = (k >> 3) & 3, j8 = k & 7;
    tjf[((((size_t)(b * 4 + s)) * 256 + j) * 4 + lg2) * 8 + j8] = v;
  }
}

// ---------------- h0 = leaky(fres @ W_emb) fused with proj [ti|tj] = h0 @ Wij ----------------
__global__ __launch_bounds__(256) void h0_proj(
    const float* __restrict__ fres, const float* __restrict__ Wemb,
    const ushort_t* __restrict__ wijf, float* __restrict__ h_out,
    float* __restrict__ ti, float* __restrict__ tjf) {
  const int m0 = blockIdx.x * 16;
  const int tid = threadIdx.x;
  const int w = tid >> 6, lane = tid & 63, l16 = lane & 15, lg = lane >> 4;
  __shared__ __align__(16) ushort_t sH[16][136];
  {
    const int row = tid >> 4, c0 = (tid & 15) * 8;
    const float* fr = fres + (size_t)(m0 + row) * 20;
    float a[8] = {0, 0, 0, 0, 0, 0, 0, 0};
    for (int k = 0; k < 20; ++k) {
      float fv = fr[k];
      float4 w0 = *(const float4*)(Wemb + k * 128 + c0);
      float4 w1 = *(const float4*)(Wemb + k * 128 + c0 + 4);
      a[0] += fv * w0.x; a[1] += fv * w0.y; a[2] += fv * w0.z; a[3] += fv * w0.w;
      a[4] += fv * w1.x; a[5] += fv * w1.y; a[6] += fv * w1.z; a[7] += fv * w1.w;
    }
#pragma unroll
    for (int x = 0; x < 8; ++x) a[x] = lk(a[x]);
    float* ho = h_out + (size_t)(m0 + row) * 128 + c0;
    *(float4*)ho = (float4){a[0], a[1], a[2], a[3]};
    *(float4*)(ho + 4) = (float4){a[4], a[5], a[6], a[7]};
    unsigned int* sh = (unsigned int*)&sH[row][c0];
    sh[0] = pk2bf(a[0], a[1]); sh[1] = pk2bf(a[2], a[3]);
    sh[2] = pk2bf(a[4], a[5]); sh[3] = pk2bf(a[6], a[7]);
  }
  __syncthreads();
  floatx4 ap[4];
#pragma unroll
  for (int q = 0; q < 4; ++q) ap[q] = (floatx4){0.f, 0.f, 0.f, 0.f};
  const shortx8* Wp = (const shortx8*)wijf;
#pragma unroll
  for (int s = 0; s < 4; ++s) {
    shortx8 af = *(const shortx8*)&sH[l16][s * 32 + lg * 8];
#pragma unroll
    for (int q = 0; q < 4; ++q)
      ap[q] = __builtin_amdgcn_mfma_f32_16x16x32_bf16(af, Wp[(s * 16 + 4 * w + q) * 64 + lane], ap[q], 0, 0, 0);
  }
#pragma unroll
  for (int q = 0; q < 4; ++q) {
    const int n = (4 * w + q) * 16 + l16;
#pragma unroll
    for (int r = 0; r < 4; ++r) proj_store(ap[q][r], m0 + lg * 4 + r, n, ti, tjf);
  }
}

// ---------------- edge kernel v4: 2 i's per block, prefetched tjf, packed epilogue ----------------
__global__ __launch_bounds__(256, 3) void edge_kernel(
    const float* __restrict__ ti, const float* __restrict__ tjf,
    const float* __restrict__ coords, const ushort_t* __restrict__ we2f,
    const float* __restrict__ W_e1, const float* __restrict__ b_e1,
    const float* __restrict__ b_e2, const float* __restrict__ W_inf,
    const float* __restrict__ b_inf, float* __restrict__ mp0, float* __restrict__ mp1) {
  const int blk = blockIdx.x;            // b(3) x ipair(7) x ch(1)
  const int b = blk >> 8, ip = (blk >> 1) & 127, ch = blk & 1;
  const int tid = threadIdx.x;
  const int w = tid >> 6, lane = tid & 63, l16 = lane & 15, lg = lane >> 4;

  __shared__ __align__(16) ushort_t sW[16384];   // 32 KB We2 fragment-linear
  __shared__ __align__(16) float sTiP[2][128];
  __shared__ __align__(16) float sWd[128];
  __shared__ __align__(16) float sD2[2][128];
  __shared__ __align__(16) float sMp[2][4][128];

  {
    shortx8* dst = (shortx8*)sW;
    const shortx8* src = (const shortx8*)we2f;
#pragma unroll
    for (int r = 0; r < 8; ++r) dst[r * 256 + tid] = src[r * 256 + tid];
  }
  {
    const int ii = tid >> 7, t2 = tid & 127;
    const int i = ip * 2 + ii;
    sTiP[ii][t2] = ti[(size_t)(b * 256 + i) * 128 + t2] + b_e1[t2];
    if (ii == 0) sWd[t2] = W_e1[256 * 128 + t2];
    const int j = ch * 128 + t2;
    float dx = coords[(size_t)(b * 256 + i) * 3 + 0] - coords[(size_t)(b * 256 + j) * 3 + 0];
    float dy = coords[(size_t)(b * 256 + i) * 3 + 1] - coords[(size_t)(b * 256 + j) * 3 + 1];
    float dz = coords[(size_t)(b * 256 + i) * 3 + 2] - coords[(size_t)(b * 256 + j) * 3 + 2];
    sD2[ii][t2] = dx * dx + dy * dy + dz * dz;
  }
  float bev[8], winfv[8];
#pragma unroll
  for (int t = 0; t < 8; ++t) {
    bev[t] = b_e2[t * 16 + l16];
    winfv[t] = W_inf[t * 16 + l16];
  }
  const float binf = b_inf[0];
  __syncthreads();

  const shortx8* sWf = (const shortx8*)sW;

#pragma unroll
  for (int ii = 0; ii < 2; ++ii) {
    const int i = ip * 2 + ii;
    float d2a[2];
    d2a[0] = sD2[ii][w * 16 + l16];
    d2a[1] = sD2[ii][64 + w * 16 + l16];

    floatx4 acc[2][8];
#pragma unroll
    for (int t = 0; t < 8; ++t) {
      acc[0][t] = (floatx4){bev[t], bev[t], bev[t], bev[t]};
      acc[1][t] = acc[0][t];
    }

    // prefetch s=0 tjf
    float4 cur0[2], cur1[2];
#pragma unroll
    for (int c = 0; c < 2; ++c) {
      const int jr = ch * 128 + c * 64 + w * 16 + l16;
      const float* tb = tjf + (((size_t)(b * 4 + 0) * 256 + jr) * 4 + lg) * 8;
      cur0[c] = *(const float4*)tb;
      cur1[c] = *(const float4*)(tb + 4);
    }

#pragma unroll
    for (int s = 0; s < 4; ++s) {
      float4 nxt0[2], nxt1[2];
      if (s < 3) {
#pragma unroll
        for (int c = 0; c < 2; ++c) {
          const int jr = ch * 128 + c * 64 + w * 16 + l16;
          const float* tb = tjf + (((size_t)(b * 4 + s + 1) * 256 + jr) * 4 + lg) * 8;
          nxt0[c] = *(const float4*)tb;
          nxt1[c] = *(const float4*)(tb + 4);
        }
      }
      const int k0 = s * 32 + lg * 8;
      floatx2 p2[4], w2[4];
#pragma unroll
      for (int x = 0; x < 4; ++x) {
        p2[x] = *(const floatx2*)&sTiP[ii][k0 + 2 * x];
        w2[x] = *(const floatx2*)&sWd[k0 + 2 * x];
      }
      shortx8 af[2];
#pragma unroll
      for (int c = 0; c < 2; ++c) {
        const floatx2 d2v = (floatx2){d2a[c], d2a[c]};
        floatx2 pr0 = (floatx2){cur0[c].x, cur0[c].y} + (p2[0] + d2v * w2[0]);
        floatx2 pr1 = (floatx2){cur0[c].z, cur0[c].w} + (p2[1] + d2v * w2[1]);
        floatx2 pr2 = (floatx2){cur1[c].x, cur1[c].y} + (p2[2] + d2v * w2[2]);
        floatx2 pr3 = (floatx2){cur1[c].z, cur1[c].w} + (p2[3] + d2v * w2[3]);
        floatx2 l0 = lk2(pr0), l1 = lk2(pr1), l2 = lk2(pr2), l3 = lk2(pr3);
        union { shortx8 s8; unsigned int u[4]; } A;
        A.u[0] = pk2bf(l0.x, l0.y); A.u[1] = pk2bf(l1.x, l1.y);
        A.u[2] = pk2bf(l2.x, l2.y); A.u[3] = pk2bf(l3.x, l3.y);
        af[c] = A.s8;
      }
#pragma unroll
      for (int tg = 0; tg < 2; ++tg) {
        shortx8 b0 = sWf[(s * 8 + tg * 4 + 0) * 64 + lane];
        shortx8 b1 = sWf[(s * 8 + tg * 4 + 1) * 64 + lane];
        shortx8 b2 = sWf[(s * 8 + tg * 4 + 2) * 64 + lane];
        shortx8 b3 = sWf[(s * 8 + tg * 4 + 3) * 64 + lane];
#pragma unroll
        for (int c = 0; c < 2; ++c) {
          acc[c][tg * 4 + 0] = __builtin_amdgcn_mfma_f32_16x16x32_bf16(af[c], b0, acc[c][tg * 4 + 0], 0, 0, 0);
          acc[c][tg * 4 + 1] = __builtin_amdgcn_mfma_f32_16x16x32_bf16(af[c], b1, acc[c][tg * 4 + 1], 0, 0, 0);
          acc[c][tg * 4 + 2] = __builtin_amdgcn_mfma_f32_16x16x32_bf16(af[c], b2, acc[c][tg * 4 + 2], 0, 0, 0);
          acc[c][tg * 4 + 3] = __builtin_amdgcn_mfma_f32_16x16x32_bf16(af[c], b3, acc[c][tg * 4 + 3], 0, 0, 0);
        }
      }
#pragma unroll
      for (int c = 0; c < 2; ++c) { cur0[c] = nxt0[c]; cur1[c] = nxt1[c]; }
    }

    // epilogue: leaky (pk), gated reduction (pk over r-pairs)
    floatx2 mpp[8];
#pragma unroll
    for (int t = 0; t < 8; ++t) mpp[t] = (floatx2){0.f, 0.f};
#pragma unroll
    for (int c = 0; c < 2; ++c) {
#pragma unroll
      for (int t = 0; t < 8; ++t) {
        floatx2 v0 = lk2((floatx2){acc[c][t][0], acc[c][t][1]});
        floatx2 v1 = lk2((floatx2){acc[c][t][2], acc[c][t][3]});
        acc[c][t][0] = v0.x; acc[c][t][1] = v0.y; acc[c][t][2] = v1.x; acc[c][t][3] = v1.y;
      }
      floatx2 q01 = (floatx2){0.f, 0.f}, q23 = (floatx2){0.f, 0.f};
#pragma unroll
      for (int t = 0; t < 8; ++t) {
        const floatx2 wv = (floatx2){winfv[t], winfv[t]};
        q01 += (floatx2){acc[c][t][0], acc[c][t][1]} * wv;
        q23 += (floatx2){acc[c][t][2], acc[c][t][3]} * wv;
      }
      float p[4] = {q01.x, q01.y, q23.x, q23.y};
#pragma unroll
      for (int off = 1; off <= 8; off <<= 1)
#pragma unroll
        for (int r = 0; r < 4; ++r) p[r] += __shfl_xor(p[r], off);
      float e[4];
#pragma unroll
      for (int r = 0; r < 4; ++r) {
        const int jg = ch * 128 + c * 64 + w * 16 + lg * 4 + r;
        float x = p[r] + binf;
        e[r] = __builtin_amdgcn_rcpf(1.f + __expf(-x));
        if (jg == i) e[r] = 0.f;
      }
      const floatx2 e01 = (floatx2){e[0], e[1]}, e23 = (floatx2){e[2], e[3]};
#pragma unroll
      for (int t = 0; t < 8; ++t) {
        mpp[t] += (floatx2){acc[c][t][0], acc[c][t][1]} * e01;
        mpp[t] += (floatx2){acc[c][t][2], acc[c][t][3]} * e23;
      }
    }
    float mp[8];
#pragma unroll
    for (int t = 0; t < 8; ++t) {
      mp[t] = mpp[t].x + mpp[t].y;
      mp[t] += __shfl_xor(mp[t], 16);
      mp[t] += __shfl_xor(mp[t], 32);
    }
    if (lg == 0) {
#pragma unroll
      for (int t = 0; t < 8; ++t) sMp[ii][w][t * 16 + l16] = mp[t];
    }
  }
  __syncthreads();
  {
    const int ii = tid >> 7, t2 = tid & 127;
    const int i = ip * 2 + ii;
    float v = sMp[ii][0][t2] + sMp[ii][1][t2] + sMp[ii][2][t2] + sMp[ii][3][t2];
    float* mpo = ch ? mp1 : mp0;
    mpo[(size_t)(b * 256 + i) * 128 + t2] = v;
  }
}

// ---------------- fused node MLP (+ next-iteration proj) ----------------
// hm = [h | mp0+mp1]; u = leaky(hm@W_h1+b_h1); h' = u@W_h2+b_h2+h; [ti|tj] = h'@Wij
__global__ __launch_bounds__(256) void node_kernel(
    const float* __restrict__ h_in, const float* __restrict__ mp0, const float* __restrict__ mp1,
    const ushort_t* __restrict__ wh1f, const float* __restrict__ b_h1,
    const ushort_t* __restrict__ wh2f, const float* __restrict__ b_h2,
    const ushort_t* __restrict__ wijf, float* __restrict__ h_out,
    float* __restrict__ ti, float* __restrict__ tjf, const int do_proj) {
  const int m0 = blockIdx.x * 16;
  const int tid = threadIdx.x;
  const int w = tid >> 6, lane = tid & 63, l16 = lane & 15, lg = lane >> 4;
  __shared__ __align__(16) ushort_t sA[16][264];
  __shared__ __align__(16) ushort_t sU[16][136];
  __shared__ __align__(16) ushort_t sHp[16][136];

  {
    const int row = tid >> 4, c0 = (tid & 15) * 16;
    unsigned int* dst = (unsigned int*)&sA[row][c0];
    if (c0 < 128) {
      const float* src = h_in + (size_t)(m0 + row) * 128 + c0;
#pragma unroll
      for (int x = 0; x < 8; ++x) dst[x] = pk2bf(src[2 * x], src[2 * x + 1]);
    } else {
      const float* s0 = mp0 + (size_t)(m0 + row) * 128 + (c0 - 128);
      const float* s1 = mp1 + (size_t)(m0 + row) * 128 + (c0 - 128);
#pragma unroll
      for (int x = 0; x < 8; ++x)
        dst[x] = pk2bf(s0[2 * x] + s1[2 * x], s0[2 * x + 1] + s1[2 * x + 1]);
    }
  }
  __syncthreads();
  // u tiles {2w, 2w+1}
  floatx4 au[2];
#pragma unroll
  for (int q = 0; q < 2; ++q) { float bv = b_h1[(2 * w + q) * 16 + l16]; au[q] = (floatx4){bv, bv, bv, bv}; }
  const shortx8* W1 = (const shortx8*)wh1f;
#pragma unroll
  for (int s = 0; s < 8; ++s) {
    shortx8 af = *(const shortx8*)&sA[l16][s * 32 + lg * 8];
#pragma unroll
    for (int q = 0; q < 2; ++q)
      au[q] = __builtin_amdgcn_mfma_f32_16x16x32_bf16(af, W1[(s * 8 + 2 * w + q) * 64 + lane], au[q], 0, 0, 0);
  }
#pragma unroll
  for (int q = 0; q < 2; ++q)
#pragma unroll
    for (int r = 0; r < 4; ++r)
      sU[lg * 4 + r][(2 * w + q) * 16 + l16] = f2bf_rhu(lk(au[q][r]));
  __syncthreads();
  // h' tiles {2w, 2w+1}
  floatx4 ah[2];
#pragma unroll
  for (int q = 0; q < 2; ++q) { float bv = b_h2[(2 * w + q) * 16 + l16]; ah[q] = (floatx4){bv, bv, bv, bv}; }
  const shortx8* W2 = (const shortx8*)wh2f;
#pragma unroll
  for (int s = 0; s < 4; ++s) {
    shortx8 af = *(const shortx8*)&sU[l16][s * 32 + lg * 8];
#pragma unroll
    for (int q = 0; q < 2; ++q)
      ah[q] = __builtin_amdgcn_mfma_f32_16x16x32_bf16(af, W2[(s * 8 + 2 * w + q) * 64 + lane], ah[q], 0, 0, 0);
  }
#pragma unroll
  for (int q = 0; q < 2; ++q) {
    const int n = (2 * w + q) * 16 + l16;
#pragma unroll
    for (int r = 0; r < 4; ++r) {
      const int m = m0 + lg * 4 + r;
      float v = ah[q][r] + h_in[(size_t)m * 128 + n];
      h_out[(size_t)m * 128 + n] = v;
      sHp[lg * 4 + r][n] = f2bf_rhu(v);
    }
  }
  if (!do_proj) return;
  __syncthreads();
  // proj tiles {4w..4w+3}
  floatx4 ap[4];
#pragma unroll
  for (int q = 0; q < 4; ++q) ap[q] = (floatx4){0.f, 0.f, 0.f, 0.f};
  const shortx8* Wp = (const shortx8*)wijf;
#pragma unroll
  for (int s = 0; s < 4; ++s) {
    shortx8 af = *(const shortx8*)&sHp[l16][s * 32 + lg * 8];
#pragma unroll
    for (int q = 0; q < 4; ++q)
      ap[q] = __builtin_amdgcn_mfma_f32_16x16x32_bf16(af, Wp[(s * 16 + 4 * w + q) * 64 + lane], ap[q], 0, 0, 0);
  }
#pragma unroll
  for (int q = 0; q < 4; ++q) {
    const int n = (4 * w + q) * 16 + l16;
#pragma unroll
    for (int r = 0; r < 4; ++r) proj_store(ap[q][r], m0 + lg * 4 + r, n, ti, tjf);
  }
}

extern "C" void kernel_launch(void* const* d_in, const int* in_sizes, int n_in,
                              void* d_out, int out_size, void* d_ws, size_t ws_size,
                              hipStream_t stream) {
  const float* fres   = (const float*)d_in[0];
  const float* coords = (const float*)d_in[1];
  const float* W_emb  = (const float*)d_in[2];
  const float* W_e1   = (const float*)d_in[3];
  const float* b_e1   = (const float*)d_in[4];
  const float* W_e2   = (const float*)d_in[5];
  const float* b_e2   = (const float*)d_in[6];
  const float* W_inf  = (const float*)d_in[7];
  const float* b_inf  = (const float*)d_in[8];
  const float* W_h1   = (const float*)d_in[9];
  const float* b_h1   = (const float*)d_in[10];
  const float* W_h2   = (const float*)d_in[11];
  const float* b_h2   = (const float*)d_in[12];
  float* out = (float*)d_out;

  char* ws = (char*)d_ws;
  float* hA  = (float*)(ws + (0 << 20));
  float* hB  = (float*)(ws + (1 << 20));
  float* tib = (float*)(ws + (2 << 20));
  float* tjf = (float*)(ws + (3 << 20));
  float* mp0 = (float*)(ws + (4 << 20));
  float* mp1 = (float*)(ws + (5 << 20));
  ushort_t* wijf = (ushort_t*)(ws + (6 << 20));
  ushort_t* we2f = wijf + 32768;
  ushort_t* wh1f = we2f + 16384;
  ushort_t* wh2f = wh1f + 32768;

  prep_w<<<384, 256, 0, stream>>>(W_e1, W_e2, W_h1, W_h2, wijf, we2f, wh1f, wh2f);
  h0_proj<<<128, 256, 0, stream>>>(fres, W_emb, wijf, hA, tib, tjf);

  edge_kernel<<<2048, 256, 0, stream>>>(tib, tjf, coords, we2f, W_e1, b_e1, b_e2, W_inf, b_inf, mp0, mp1);
  node_kernel<<<128, 256, 0, stream>>>(hA, mp0, mp1, wh1f, b_h1, wh2f, b_h2, wijf, hB, tib, tjf, 1);

  edge_kernel<<<2048, 256, 0, stream>>>(tib, tjf, coords, we2f, W_e1, b_e1, b_e2, W_inf, b_inf, mp0, mp1);
  node_kernel<<<128, 256, 0, stream>>>(hB, mp0, mp1, wh1f, b_h1, wh2f, b_h2, wijf, out, tib, tjf, 0);
}